// Round 1
// baseline (362.771 us; speedup 1.0000x reference)
//
#include <hip/hip_runtime.h>
#include <hip/hip_bf16.h>
#include <stdint.h>

// B=524288 rows, H=64, D=1. All inputs fp32, output fp32 [B,1].
// Strategy: fold W2 into W_ih -> Wc[256x128] bf16 (fragment-order in d_ws),
// bf16 MFMA 16x16x32 for gates, fp32 transcendental epilogue. Memory-bound
// target ~44us (276 MB HBM traffic).

typedef __attribute__((ext_vector_type(8))) short   short8;
typedef __attribute__((ext_vector_type(8))) __bf16  bf16x8;
typedef __attribute__((ext_vector_type(4))) float   floatx4;

__device__ __forceinline__ unsigned short f2bf_bits(float x){
    unsigned u = __builtin_bit_cast(unsigned, x);
    u = u + 0x7fffu + ((u >> 16) & 1u);          // RNE
    return (unsigned short)(u >> 16);
}
__device__ __forceinline__ float bf2f(unsigned short s){
    unsigned u = ((unsigned)s) << 16;
    return __builtin_bit_cast(float, u);
}
__device__ __forceinline__ float sigm(float x){ return 1.0f / (1.0f + __expf(-x)); }
__device__ __forceinline__ float tanh_fast(float x){ return 1.0f - 2.0f / (1.0f + __expf(2.0f*x)); }

// ---------------------------------------------------------------------------
// Prep: Wc[n][k] (k<64: sum_h W_ih[n][h]*W2[h][k]; k>=64: W_hh[n][k-64]) in
// bf16 MFMA-B fragment order; bias_c[n] = b_ih+b_hh+sum_h W_ih[n][h]*b2[h].
// Fragment order: chunk (T=n>>4, s=k>>5): lane l = ((k>>3)&3)*16 + (n&15)
// holds 8 shorts at chunk*512 + l*8 + (k&7).
// ---------------------------------------------------------------------------
__global__ __launch_bounds__(256) void prep_kernel(
    const float* __restrict__ W2, const float* __restrict__ b2,
    const float* __restrict__ W_ih, const float* __restrict__ W_hh,
    const float* __restrict__ b_ih, const float* __restrict__ b_hh,
    unsigned short* __restrict__ wc, float* __restrict__ biasc)
{
    __shared__ float W2s[64*64];
    __shared__ float b2s[64];
    __shared__ float wihs[16*64];
    const int tid = threadIdx.x;
    const int b   = blockIdx.x;          // 0..15, rows n0=b*16..+15

    for (int i = 0; i < 4; i++){
        int idx = i*1024 + tid*4;
        *(float4*)(W2s + idx) = *(const float4*)(W2 + idx);
    }
    if (tid < 64) b2s[tid] = b2[tid];
    {
        int idx = tid*4;
        *(float4*)(wihs + idx) = *(const float4*)(W_ih + b*16*64 + idx);
    }
    __syncthreads();

    const int nl = tid >> 4;             // 0..15
    const int n  = b*16 + nl;            // global gate row
    const int jg = tid & 15;             // j-group
    const int j  = jg*4;
    const int T  = n >> 4;

    float a0=0.f, a1=0.f, a2=0.f, a3=0.f;
    for (int h = 0; h < 64; h++){
        float wv = wihs[nl*64 + h];
        const float* w2r = W2s + h*64 + j;
        a0 += wv*w2r[0]; a1 += wv*w2r[1]; a2 += wv*w2r[2]; a3 += wv*w2r[3];
    }
    // store 4 bf16 at fragment position for k
    auto store4 = [&](int k, float v0, float v1, float v2, float v3){
        int s    = k >> 5;
        int lane = ((k >> 3) & 3)*16 + (n & 15);
        int off  = (T*4 + s)*512 + lane*8 + (k & 7);     // in shorts; 8B aligned
        ushort4 v; v.x=f2bf_bits(v0); v.y=f2bf_bits(v1); v.z=f2bf_bits(v2); v.w=f2bf_bits(v3);
        *(ushort4*)(wc + off) = v;
    };
    store4(j, a0, a1, a2, a3);
    {
        const float* src = W_hh + n*64 + j;
        store4(64 + j, src[0], src[1], src[2], src[3]);
    }
    if (jg == 0){
        float s = b_ih[n] + b_hh[n];
        for (int h = 0; h < 64; h++) s += wihs[nl*64 + h]*b2s[h];
        biasc[n] = s;
    }
}

// ---------------------------------------------------------------------------
// Main: one block = 64 rows. 512 threads = 8 waves; wave w computes all 64
// rows x 32 gate-cols [32w,32w+32) via mfma_f32_16x16x32_bf16.
// ---------------------------------------------------------------------------
__global__ __launch_bounds__(512, 4) void main_kernel(
    const float* __restrict__ grad, const float* __restrict__ param,
    const float* __restrict__ mom,  const float* __restrict__ h0,
    const float* __restrict__ c0,   const float* __restrict__ W1,
    const float* __restrict__ b1,   const float* __restrict__ Wout,
    const float* __restrict__ bout,
    const unsigned short* __restrict__ wc, const float* __restrict__ biasc,
    float* __restrict__ out)
{
    __shared__ unsigned short A_l[64*136];      // 64 rows x (128 + 8 pad) bf16
    __shared__ unsigned short gates_l[4*64*68]; // [gate][row][j(+4 pad)] bf16
    __shared__ float psum_l[64*17];
    __shared__ float feats_l[3*64];             // g, p, m
    __shared__ float w1_l[3*64];                // transposed W1
    __shared__ float b1_l[64];
    __shared__ float wout_l[64];
    __shared__ float bias_l[256];

    const int tid  = threadIdx.x;
    const int lane = tid & 63;
    const int w    = tid >> 6;                  // wave 0..7
    const long row0 = (long)blockIdx.x * 64;

    // ---- P0: stage h0 (bf16) + small tables + feats ----
    for (int it = 0; it < 2; it++){
        int flat = it*2048 + tid*4;
        int row = flat >> 6, col = flat & 63;
        float4 v = *(const float4*)(h0 + (row0 + row)*64 + col);
        ushort4 s; s.x=f2bf_bits(v.x); s.y=f2bf_bits(v.y); s.z=f2bf_bits(v.z); s.w=f2bf_bits(v.w);
        *(ushort4*)(A_l + row*136 + 64 + col) = s;
    }
    if (tid < 192)      w1_l[(tid % 3)*64 + tid/3] = W1[tid];   // W1 is [64][3]
    else if (tid < 256) b1_l[tid - 192]  = b1[tid - 192];
    else if (tid < 320) wout_l[tid - 256] = Wout[tid - 256];
    else if (tid >= 448){
        int r = tid - 448;
        float g = grad[row0 + r], p = param[row0 + r], mo = mom[row0 + r];
        feats_l[r] = g; feats_l[64 + r] = p; feats_l[128 + r] = 0.9f*mo + g;
    }
    if (tid < 256) bias_l[tid] = biasc[tid];
    __syncthreads();

    // ---- P1: r = relu(feats @ W1.T + b1) -> A_l cols 0..63 ----
    {
        int row = tid & 63;
        int jb  = (tid >> 6) * 8;               // wave-uniform
        float g = feats_l[row], p = feats_l[64+row], m = feats_l[128+row];
        ushort4 sa, sb;
        unsigned short tv[8];
        #pragma unroll
        for (int jj = 0; jj < 8; jj++){
            int j = jb + jj;
            float v = w1_l[j]*g + w1_l[64+j]*p + w1_l[128+j]*m + b1_l[j];
            v = v > 0.f ? v : 0.f;
            tv[jj] = f2bf_bits(v);
        }
        sa.x=tv[0]; sa.y=tv[1]; sa.z=tv[2]; sa.w=tv[3];
        sb.x=tv[4]; sb.y=tv[5]; sb.z=tv[6]; sb.w=tv[7];
        *(ushort4*)(A_l + row*136 + jb)     = sa;
        *(ushort4*)(A_l + row*136 + jb + 4) = sb;
    }
    __syncthreads();

    // ---- P2: MFMA gates = [r|h0] @ Wc.T + bias ----
    const int l15 = lane & 15, q = lane >> 4;
    floatx4 acc[4][2];
    bf16x8  bfr[2][4];
    #pragma unroll
    for (int t = 0; t < 2; t++){
        int T = w*2 + t;
        float bv = bias_l[T*16 + l15];
        #pragma unroll
        for (int m = 0; m < 4; m++) acc[m][t] = (floatx4){bv, bv, bv, bv};
        #pragma unroll
        for (int s = 0; s < 4; s++)
            bfr[t][s] = __builtin_bit_cast(bf16x8,
                *(const short8*)(wc + (T*4 + s)*512 + lane*8));
    }
    #pragma unroll
    for (int m = 0; m < 4; m++){
        bf16x8 afr[4];
        const unsigned short* abase = A_l + (m*16 + l15)*136 + q*8;
        #pragma unroll
        for (int s = 0; s < 4; s++)
            afr[s] = __builtin_bit_cast(bf16x8, *(const short8*)(abase + s*32));
        #pragma unroll
        for (int t = 0; t < 2; t++)
            #pragma unroll
            for (int s = 0; s < 4; s++)
                acc[m][t] = __builtin_amdgcn_mfma_f32_16x16x32_bf16(
                                afr[s], bfr[t][s], acc[m][t], 0, 0, 0);
    }
    // write gates (bf16) to LDS: gates_l[n>>6][row][n&63]
    #pragma unroll
    for (int t = 0; t < 2; t++){
        int n = (w*2 + t)*16 + l15;
        int gg = n >> 6, j = n & 63;
        #pragma unroll
        for (int m = 0; m < 4; m++)
            #pragma unroll
            for (int r = 0; r < 4; r++){
                int row = m*16 + q*4 + r;
                gates_l[(gg*64 + row)*68 + j] = f2bf_bits(acc[m][t][r]);
            }
    }
    __syncthreads();

    // ---- P3: LSTM elementwise + partial output dot ----
    for (int it = 0; it < 2; it++){
        int task = it*512 + tid;
        int row  = task >> 4;
        int j0   = (task & 15) * 4;
        float4 c0v = *(const float4*)(c0 + (row0 + row)*64 + j0);
        const unsigned short* gp = gates_l + row*68 + j0;
        ushort4 iv = *(const ushort4*)(gp + 0*64*68);
        ushort4 fv = *(const ushort4*)(gp + 1*64*68);
        ushort4 gv = *(const ushort4*)(gp + 2*64*68);
        ushort4 ov = *(const ushort4*)(gp + 3*64*68);
        float c0a[4] = {c0v.x, c0v.y, c0v.z, c0v.w};
        unsigned short ia[4] = {iv.x, iv.y, iv.z, iv.w};
        unsigned short fa[4] = {fv.x, fv.y, fv.z, fv.w};
        unsigned short ga[4] = {gv.x, gv.y, gv.z, gv.w};
        unsigned short oa[4] = {ov.x, ov.y, ov.z, ov.w};
        float part = 0.f;
        #pragma unroll
        for (int k = 0; k < 4; k++){
            float i_ = sigm(bf2f(ia[k]));
            float f_ = sigm(bf2f(fa[k]));
            float g_ = tanh_fast(bf2f(ga[k]));
            float o_ = sigm(bf2f(oa[k]));
            float c1 = f_*c0a[k] + i_*g_;
            float h1 = o_*tanh_fast(c1);
            part += h1 * wout_l[j0 + k];
        }
        psum_l[row*17 + (task & 15)] = part;
    }
    __syncthreads();

    // ---- P4: reduce 16 partials per row, add b_out, store ----
    if (tid < 64){
        float s = bout[0];
        #pragma unroll
        for (int k = 0; k < 16; k++) s += psum_l[tid*17 + k];
        out[row0 + tid] = s;
    }
}

extern "C" void kernel_launch(void* const* d_in, const int* in_sizes, int n_in,
                              void* d_out, int out_size, void* d_ws, size_t ws_size,
                              hipStream_t stream)
{
    const float* grad  = (const float*)d_in[0];
    const float* param = (const float*)d_in[1];
    const float* mom   = (const float*)d_in[2];
    const float* h0    = (const float*)d_in[3];
    const float* c0    = (const float*)d_in[4];
    const float* W1    = (const float*)d_in[5];
    const float* b1    = (const float*)d_in[6];
    const float* W2    = (const float*)d_in[7];
    const float* b2    = (const float*)d_in[8];
    const float* W_ih  = (const float*)d_in[9];
    const float* W_hh  = (const float*)d_in[10];
    const float* b_ih  = (const float*)d_in[11];
    const float* b_hh  = (const float*)d_in[12];
    const float* Wout  = (const float*)d_in[13];
    const float* bout  = (const float*)d_in[14];

    unsigned short* wc = (unsigned short*)d_ws;
    float* biasc       = (float*)((char*)d_ws + 65536);

    prep_kernel<<<16, 256, 0, stream>>>(W2, b2, W_ih, W_hh, b_ih, b_hh, wc, biasc);

    const int nblocks = 524288 / 64;   // 8192
    main_kernel<<<nblocks, 512, 0, stream>>>(grad, param, mom, h0, c0,
                                             W1, b1, Wout, bout, wc, biasc,
                                             (float*)d_out);
}

// Round 4
// 310.575 us; speedup vs baseline: 1.1681x; 1.1681x over previous
//
#include <hip/hip_runtime.h>
#include <hip/hip_bf16.h>
#include <stdint.h>

// B=524288, H=64, D=1. fp32 in/out.
// R2 structure, R3 compile fix (pk2 without __builtin_bit_cast on class type).
// Each wave computes 16 batch rows x all 256 gate cols via 16 MFMA C-tiles;
// for fixed (row,j) the four gates i,f,g,o sit in tiles gate*4+(j>>4) at the
// SAME lane -> LSTM epilogue fully in registers (fp32 gates, no LDS round
// trip). A-fragments built in registers. Wc staged once per block to LDS
// (single barrier). Output dot via 16-lane shuffle butterfly.

typedef __attribute__((ext_vector_type(8))) __bf16  bf16x8;
typedef __attribute__((ext_vector_type(4))) float   floatx4;

__device__ __forceinline__ unsigned short f2bf_bits(float x){
    unsigned u = __builtin_bit_cast(unsigned, x);
    u = u + 0x7fffu + ((u >> 16) & 1u);          // RNE
    return (unsigned short)(u >> 16);
}
__device__ __forceinline__ unsigned pk2(float lo, float hi){
    return ((unsigned)f2bf_bits(hi) << 16) | (unsigned)f2bf_bits(lo);
}
__device__ __forceinline__ bf16x8 pack8(float4 a, float4 b){
    union { unsigned u[4]; bf16x8 v; } p;
    p.u[0] = pk2(a.x, a.y); p.u[1] = pk2(a.z, a.w);
    p.u[2] = pk2(b.x, b.y); p.u[3] = pk2(b.z, b.w);
    return p.v;
}
__device__ __forceinline__ float sigm(float x){
    float e = __builtin_amdgcn_exp2f(-1.442695041f * x);
    return __builtin_amdgcn_rcpf(1.0f + e);
}
__device__ __forceinline__ float tanh_fast(float x){
    float e = __builtin_amdgcn_exp2f(2.885390082f * x);   // e^(2x)
    return 1.0f - 2.0f * __builtin_amdgcn_rcpf(1.0f + e);
}

// ---------------------------------------------------------------------------
// Prep (unchanged, proven correct in R1): Wc[256x128] bf16 in MFMA-B fragment
// order; biasc[n] = b_ih+b_hh+W_ih@b2.
// ---------------------------------------------------------------------------
__global__ __launch_bounds__(256) void prep_kernel(
    const float* __restrict__ W2, const float* __restrict__ b2,
    const float* __restrict__ W_ih, const float* __restrict__ W_hh,
    const float* __restrict__ b_ih, const float* __restrict__ b_hh,
    unsigned short* __restrict__ wc, float* __restrict__ biasc)
{
    __shared__ float W2s[64*64];
    __shared__ float b2s[64];
    __shared__ float wihs[16*64];
    const int tid = threadIdx.x;
    const int b   = blockIdx.x;          // 0..15

    for (int i = 0; i < 4; i++){
        int idx = i*1024 + tid*4;
        *(float4*)(W2s + idx) = *(const float4*)(W2 + idx);
    }
    if (tid < 64) b2s[tid] = b2[tid];
    {
        int idx = tid*4;
        *(float4*)(wihs + idx) = *(const float4*)(W_ih + b*16*64 + idx);
    }
    __syncthreads();

    const int nl = tid >> 4;
    const int n  = b*16 + nl;
    const int jg = tid & 15;
    const int j  = jg*4;
    const int T  = n >> 4;

    float a0=0.f, a1=0.f, a2=0.f, a3=0.f;
    for (int h = 0; h < 64; h++){
        float wv = wihs[nl*64 + h];
        const float* w2r = W2s + h*64 + j;
        a0 += wv*w2r[0]; a1 += wv*w2r[1]; a2 += wv*w2r[2]; a3 += wv*w2r[3];
    }
    auto store4 = [&](int k, float v0, float v1, float v2, float v3){
        int s    = k >> 5;
        int lane = ((k >> 3) & 3)*16 + (n & 15);
        int off  = (T*4 + s)*512 + lane*8 + (k & 7);
        ushort4 v; v.x=f2bf_bits(v0); v.y=f2bf_bits(v1); v.z=f2bf_bits(v2); v.w=f2bf_bits(v3);
        *(ushort4*)(wc + off) = v;
    };
    store4(j, a0, a1, a2, a3);
    {
        const float* src = W_hh + n*64 + j;
        store4(64 + j, src[0], src[1], src[2], src[3]);
    }
    if (jg == 0){
        float s = b_ih[n] + b_hh[n];
        for (int h = 0; h < 64; h++) s += wihs[nl*64 + h]*b2s[h];
        biasc[n] = s;
    }
}

// ---------------------------------------------------------------------------
// Main: 512 threads = 8 waves, 128 rows/block, 4096 blocks.
// Wave w: rows [row0+16w, row0+16w+16), all 256 gate cols.
// ---------------------------------------------------------------------------
__global__ __launch_bounds__(512, 4) void main_kernel(
    const float* __restrict__ grad, const float* __restrict__ param,
    const float* __restrict__ mom,  const float* __restrict__ h0,
    const float* __restrict__ c0,   const float* __restrict__ W1,
    const float* __restrict__ b1,   const float* __restrict__ Wout,
    const float* __restrict__ bout,
    const unsigned short* __restrict__ wc, const float* __restrict__ biasc,
    float* __restrict__ out)
{
    __shared__ __align__(16) unsigned short wc_l[32768];  // 64 KB
    __shared__ float  bias_l[256];
    __shared__ float4 w1p_l[64];                          // {W1[j][0..2], b1[j]}

    const int tid  = threadIdx.x;
    const int lane = tid & 63;
    const int w    = tid >> 6;
    const int l15  = lane & 15;
    const int q    = lane >> 4;
    const long row0 = (long)blockIdx.x * 128;

    // ---- stage Wc + tables into LDS (single barrier) ----
    {
        const float4* src = (const float4*)wc;
        float4*       dst = (float4*)wc_l;
        #pragma unroll
        for (int i = 0; i < 8; i++)
            dst[i*512 + tid] = src[i*512 + tid];
    }
    if (tid < 256) bias_l[tid] = biasc[tid];
    if (tid >= 256 && tid < 320){
        int j = tid - 256;
        w1p_l[j] = make_float4(W1[j*3], W1[j*3+1], W1[j*3+2], b1[j]);
    }

    // ---- per-lane A-fragment build (no LDS) ----
    const long rA = row0 + w*16 + l15;          // this lane's A row
    float g = grad[rA], p = param[rA], mo = mom[rA];
    float m = 0.9f*mo + g;

    // h0 fragments (k = 64..128)
    const float* hrow = h0 + rA*64;
    float4 ha = *(const float4*)(hrow + q*8);
    float4 hb = *(const float4*)(hrow + q*8 + 4);
    float4 hc = *(const float4*)(hrow + 32 + q*8);
    float4 hd = *(const float4*)(hrow + 32 + q*8 + 4);

    __syncthreads();   // wc_l / w1p_l ready

    // r fragments (k = 0..64): r[j] = relu(W1[j]·feats + b1[j])
    float rv[16];
    #pragma unroll
    for (int s = 0; s < 2; s++)
        #pragma unroll
        for (int jj = 0; jj < 8; jj++){
            int j = s*32 + q*8 + jj;
            float4 wr = w1p_l[j];
            float v = fmaf(wr.x, g, fmaf(wr.y, p, fmaf(wr.z, m, wr.w)));
            rv[s*8+jj] = v > 0.f ? v : 0.f;
        }
    bf16x8 afr[4];
    afr[0] = pack8(make_float4(rv[0],rv[1],rv[2],rv[3]),
                   make_float4(rv[4],rv[5],rv[6],rv[7]));
    afr[1] = pack8(make_float4(rv[8],rv[9],rv[10],rv[11]),
                   make_float4(rv[12],rv[13],rv[14],rv[15]));
    afr[2] = pack8(ha, hb);
    afr[3] = pack8(hc, hd);

    // ---- MFMA: 16 tiles, gates[row][n] for n = T*16+l15, row = q*4+r ----
    floatx4 acc[16];
    #pragma unroll
    for (int T = 0; T < 16; T++){
        float bv = bias_l[T*16 + l15];
        const unsigned short* cb = wc_l + T*2048 + lane*8;
        bf16x8 b0 = *(const bf16x8*)(cb);
        bf16x8 b1f = *(const bf16x8*)(cb + 512);
        bf16x8 b2f = *(const bf16x8*)(cb + 1024);
        bf16x8 b3f = *(const bf16x8*)(cb + 1536);
        acc[T] = __builtin_amdgcn_mfma_f32_16x16x32_bf16(afr[0], b0,
                     (floatx4){bv, bv, bv, bv}, 0, 0, 0);
        acc[T] = __builtin_amdgcn_mfma_f32_16x16x32_bf16(afr[1], b1f, acc[T], 0, 0, 0);
        acc[T] = __builtin_amdgcn_mfma_f32_16x16x32_bf16(afr[2], b2f, acc[T], 0, 0, 0);
        acc[T] = __builtin_amdgcn_mfma_f32_16x16x32_bf16(afr[3], b3f, acc[T], 0, 0, 0);
    }

    // ---- LSTM epilogue in registers ----
    // lane's epilogue rows: row0 + 16w + q*4 + r ; cols j = jh*16 + l15
    // gates: i=acc[jh], f=acc[4+jh], g=acc[8+jh], o=acc[12+jh], element r.
    const float* c0base = c0 + (row0 + w*16 + q*4)*64 + l15;
    float c0v[4][4];
    #pragma unroll
    for (int jh = 0; jh < 4; jh++)
        #pragma unroll
        for (int r = 0; r < 4; r++)
            c0v[jh][r] = c0base[r*64 + jh*16];

    float wo[4];
    #pragma unroll
    for (int jh = 0; jh < 4; jh++) wo[jh] = Wout[jh*16 + l15];
    const float bout0 = bout[0];

    float red[4] = {0.f, 0.f, 0.f, 0.f};
    #pragma unroll
    for (int jh = 0; jh < 4; jh++)
        #pragma unroll
        for (int r = 0; r < 4; r++){
            float iv = sigm(acc[jh][r]);
            float fv = sigm(acc[4+jh][r]);
            float gv = tanh_fast(acc[8+jh][r]);
            float ov = sigm(acc[12+jh][r]);
            float c1 = fmaf(fv, c0v[jh][r], iv*gv);
            float h1 = ov * tanh_fast(c1);
            red[r] = fmaf(h1, wo[jh], red[r]);
        }

    // ---- reduce over l15 (16-lane butterfly), store ----
    #pragma unroll
    for (int mset = 1; mset < 16; mset <<= 1)
        #pragma unroll
        for (int r = 0; r < 4; r++)
            red[r] += __shfl_xor(red[r], mset, 64);

    if (l15 == 0){
        long orow = row0 + w*16 + q*4;
        #pragma unroll
        for (int r = 0; r < 4; r++)
            out[orow + r] = red[r] + bout0;
    }
}

extern "C" void kernel_launch(void* const* d_in, const int* in_sizes, int n_in,
                              void* d_out, int out_size, void* d_ws, size_t ws_size,
                              hipStream_t stream)
{
    const float* grad  = (const float*)d_in[0];
    const float* param = (const float*)d_in[1];
    const float* mom   = (const float*)d_in[2];
    const float* h0    = (const float*)d_in[3];
    const float* c0    = (const float*)d_in[4];
    const float* W1    = (const float*)d_in[5];
    const float* b1    = (const float*)d_in[6];
    const float* W2    = (const float*)d_in[7];
    const float* b2    = (const float*)d_in[8];
    const float* W_ih  = (const float*)d_in[9];
    const float* W_hh  = (const float*)d_in[10];
    const float* b_ih  = (const float*)d_in[11];
    const float* b_hh  = (const float*)d_in[12];
    const float* Wout  = (const float*)d_in[13];
    const float* bout  = (const float*)d_in[14];

    unsigned short* wc = (unsigned short*)d_ws;
    float* biasc       = (float*)((char*)d_ws + 65536);

    prep_kernel<<<16, 256, 0, stream>>>(W2, b2, W_ih, W_hh, b_ih, b_hh, wc, biasc);

    const int nblocks = 524288 / 128;   // 4096
    main_kernel<<<nblocks, 512, 0, stream>>>(grad, param, mom, h0, c0,
                                             W1, b1, Wout, bout, wc, biasc,
                                             (float*)d_out);
}